// Round 1
// baseline (93.456 us; speedup 1.0000x reference)
//
#include <hip/hip_runtime.h>
#include <math.h>

// FFF sparse tree forward.
// Shapes (fixed by setup_inputs): B=16384, D_IN=D_OUT=768, DEPTH=11, n_nodes=4095.
// x: [B,768] f32; w1s: [n_nodes*768] f32 (W1[node][d] = w1s[node*768+d]);
// w2s: [n_nodes,768] f32; out: [B,768] f32.
//
// Design: one wave (64 lanes) per sample. Each lane owns 12 of the 768 dims
// (as 3 float4, strided lane + j*64 for coalescing). x row and output
// accumulator live in registers. Per level: gather W1 row + w2 row (issued
// together, both indexed by current node), f64 dot + butterfly reduce for the
// routing sign (matches exact-sum sign to ~1e-13), exact-erf GELU, fma into acc.

#define FFF_DEPTH 11
#define FFF_D 768          // d_in == d_out
#define FFF_NF4 3          // float4 per lane: 768 / 4 / 64

__device__ __forceinline__ double wave_reduce_add_f64(double v) {
#pragma unroll
    for (int m = 32; m > 0; m >>= 1) {
        v += __shfl_xor(v, m, 64);
    }
    return v;
}

__global__ __launch_bounds__(256) void fff_sparse_kernel(
    const float* __restrict__ x,
    const float* __restrict__ w1s,
    const float* __restrict__ w2s,
    float* __restrict__ out,
    int B)
{
    const int wave = threadIdx.x >> 6;
    const int lane = threadIdx.x & 63;
    const int b = blockIdx.x * 4 + wave;
    if (b >= B) return;

    const float4* __restrict__ xf4  = (const float4*)x;
    const float4* __restrict__ w1f4 = (const float4*)w1s;
    const float4* __restrict__ w2f4 = (const float4*)w2s;

    // Load x row into registers (12 f32/lane), coalesced float4.
    const int row_f4 = FFF_D / 4;           // 192
    const int xb = b * row_f4 + lane;
    float4 xv[FFF_NF4];
#pragma unroll
    for (int j = 0; j < FFF_NF4; ++j) xv[j] = xf4[xb + j * 64];

    float4 acc[FFF_NF4];
#pragma unroll
    for (int j = 0; j < FFF_NF4; ++j) acc[j] = make_float4(0.f, 0.f, 0.f, 0.f);

    int node = 0;
#pragma unroll
    for (int lvl = 0; lvl <= FFF_DEPTH; ++lvl) {
        const int base = node * row_f4 + lane;

        // Issue both gathers up front (both depend only on current node).
        float4 a[FFF_NF4], c[FFF_NF4];
#pragma unroll
        for (int j = 0; j < FFF_NF4; ++j) a[j] = w1f4[base + j * 64];
#pragma unroll
        for (int j = 0; j < FFF_NF4; ++j) c[j] = w2f4[base + j * 64];

        // Routing dot in f64 for sign fidelity.
        double p = 0.0;
#pragma unroll
        for (int j = 0; j < FFF_NF4; ++j) {
            p += (double)xv[j].x * (double)a[j].x;
            p += (double)xv[j].y * (double)a[j].y;
            p += (double)xv[j].z * (double)a[j].z;
            p += (double)xv[j].w * (double)a[j].w;
        }
        p = wave_reduce_add_f64(p);   // all lanes hold the full sum

        const float logit = (float)p;
        // Exact GELU: x * 0.5 * (1 + erf(x / sqrt(2)))
        const float act = 0.5f * logit * (1.0f + erff(logit * 0.70710678118654752440f));

#pragma unroll
        for (int j = 0; j < FFF_NF4; ++j) {
            acc[j].x = fmaf(act, c[j].x, acc[j].x);
            acc[j].y = fmaf(act, c[j].y, acc[j].y);
            acc[j].z = fmaf(act, c[j].z, acc[j].z);
            acc[j].w = fmaf(act, c[j].w, acc[j].w);
        }

        node = node * 2 + 1 + (p >= 0.0 ? 1 : 0);
    }

    float4* __restrict__ of4 = (float4*)out;
    const int ob = b * row_f4 + lane;
#pragma unroll
    for (int j = 0; j < FFF_NF4; ++j) of4[ob + j * 64] = acc[j];
}

extern "C" void kernel_launch(void* const* d_in, const int* in_sizes, int n_in,
                              void* d_out, int out_size, void* d_ws, size_t ws_size,
                              hipStream_t stream) {
    const float* x   = (const float*)d_in[0];
    const float* w1s = (const float*)d_in[1];
    const float* w2s = (const float*)d_in[2];
    float* out = (float*)d_out;

    const int B = out_size / FFF_D;          // 16384
    const int blocks = (B + 3) / 4;          // 4 waves (samples) per 256-thread block

    fff_sparse_kernel<<<blocks, 256, 0, stream>>>(x, w1s, w2s, out, B);
}